// Round 14
// baseline (4317.069 us; speedup 1.0000x reference)
//
#include <hip/hip_runtime.h>
#include <stdint.h>
#include <math.h>

#define NB   16
#define HF   128
#define WF   128
#define NA   9
#define HW   (HF*WF)          // 16384
#define NTOT (HW*NA)          // 147456
#define PRE  12000
#define POST 2000
#define CAP  16384
#define CHUNK 2048
#define NPH  6

// ws layout (bytes)
#define OFF_HIST  0u
#define SZ_HIST   (NB*65536u*4u)            // 4,194,304
#define OFF_META  (OFF_HIST + SZ_HIST)
#define SZ_META   4096u   // words: [0..15] cutoff | [32..47] nk | [256+b*16] gather count (64B-padded)
#define OFF_CAND  (OFF_META + SZ_META)
#define SZ_CAND   (NB*CAP*8u)               // 2,097,152
#define OFF_TB    (OFF_CAND + SZ_CAND)
#define SZ_TB     (5u*NB*PRE*4u)            // 3,840,000
#define OFF_KEEP  (OFF_TB + SZ_TB)
#define SZ_KEEP   (NB*POST*4u)              // 128,000
#define OFF_PRES  (OFF_KEEP + SZ_KEEP)
#define SZ_PRES   (NB*32u*8u)               // 4,096
#define OFF_M     (OFF_PRES + SZ_PRES)
#define SZ_M      ((size_t)NB*CHUNK*32u*8u) // 8,388,608
#define OFF_KBOX  (OFF_M + SZ_M)
#define SZ_KBOX   (5u*NB*POST*4u)           // 640,000  (total ~19.4 MB)

#define M_CNT(b)  (256 + (b)*16)

// base anchors = classic py-faster-rcnn table minus 1 (base [0,0,15,15]); a8.y2=359.
__constant__ float c_ax1[NA] = {-84.f,-176.f,-360.f,-56.f,-120.f,-248.f,-36.f,-80.f,-168.f};
__constant__ float c_ay1[NA] = {-40.f,-88.f,-184.f,-56.f,-120.f,-248.f,-80.f,-168.f,-344.f};
__constant__ float c_ax2[NA] = { 99.f, 191.f, 375.f, 71.f, 135.f, 263.f, 51.f, 95.f, 183.f};
__constant__ float c_ay2[NA] = { 55.f, 103.f, 199.f, 71.f, 135.f, 263.f, 95.f, 183.f, 359.f};

__device__ __forceinline__ uint32_t score_key(float f){
  uint32_t b = __float_as_uint(f);
  uint32_t u = (b & 0x80000000u) ? ~b : (b | 0x80000000u);
  return ~u;   // ascending key = descending score; idx in low bits -> stable ties
}

__device__ __forceinline__ bool iou_gt(float ax1,float ay1,float ax2,float ay2,float aa,
                                       float bx1,float by1,float bx2,float by2,float ba){
  float xx1 = fmaxf(ax1,bx1);
  float yy1 = fmaxf(ay1,by1);
  float xx2 = fminf(ax2,bx2);
  float yy2 = fminf(ay2,by2);
  float w = fmaxf(__fadd_rn(__fsub_rn(xx2,xx1),1.0f), 0.0f);
  float h = fmaxf(__fadd_rn(__fsub_rn(yy2,yy1),1.0f), 0.0f);
  float inter = __fmul_rn(w,h);
  float denom = __fsub_rn(__fadd_rn(aa,ba), inter);
  float iou   = __fdiv_rn(inter, denom);
  return iou > 0.7f;
}

// -------- pass 1: histogram of score keys (top 16 bits) --------
__global__ void prep_k(const float* __restrict__ scores, uint32_t* __restrict__ hist){
  int g = blockIdx.x*256 + threadIdx.x;
  if (g >= NB*NTOT) return;
  int hw = g & (HW-1);
  int t  = g >> 14;
  int ch = t % NA;
  int b  = t / NA;
  float s = scores[((size_t)(b*2*NA + NA + ch) << 14) + hw];
  uint32_t k = score_key(s);
  atomicAdd(&hist[((uint32_t)b<<16) + (k>>16)], 1u);
}

// -------- pass 2: find cutoff bucket per batch --------
__global__ __launch_bounds__(1024) void scanhist_k(const uint32_t* __restrict__ hist,
                                                   uint32_t* __restrict__ meta){
  int b = blockIdx.x, t = threadIdx.x;
  const uint32_t* hh = hist + ((uint32_t)b<<16);
  int base = t<<6;
  uint32_t s=0;
  for (int i=0;i<64;i++) s += hh[base+i];
  __shared__ uint32_t part[1024];
  part[t]=s; __syncthreads();
  for (int off=1; off<1024; off<<=1){
    uint32_t v = (t>=off)? part[t-off] : 0u;
    __syncthreads();
    part[t] += v;
    __syncthreads();
  }
  uint32_t incl = part[t], excl = incl - s;
  if (excl < PRE && incl >= PRE){
    uint32_t run = excl;
    for (int i=0;i<64;i++){
      run += hh[base+i];
      if (run >= PRE){ meta[b] = (uint32_t)(base+i); break; }
    }
  }
}

// -------- pass 3: gather (block-aggregated atomics) --------
__global__ __launch_bounds__(256) void gather_k(const float* __restrict__ scores,
                                                uint32_t* __restrict__ meta,
                                                uint64_t* __restrict__ cand){
  int g = blockIdx.x*256 + threadIdx.x;
  int hw = g & (HW-1);
  int t  = g >> 14;
  int ch = t % NA;
  int b  = t / NA;
  float s = scores[((size_t)(b*2*NA + NA + ch) << 14) + hw];
  uint32_t k = score_key(s);
  bool sel = (k>>16) <= meta[b];
  unsigned long long m = __ballot(sel);
  int wid  = threadIdx.x >> 6;
  int lane = threadIdx.x & 63;
  __shared__ uint32_t woff[4];
  __shared__ uint32_t sbase;
  if (lane==0) woff[wid] = __popcll(m);
  __syncthreads();
  if (threadIdx.x==0){
    uint32_t a=0;
    #pragma unroll
    for (int i=0;i<4;i++){ uint32_t c=woff[i]; woff[i]=a; a+=c; }
    sbase = a ? atomicAdd(&meta[M_CNT(b)], a) : 0u;
  }
  __syncthreads();
  if (sel){
    uint32_t pos = sbase + woff[wid] + (uint32_t)__popcll(m & ((1ULL<<lane)-1ULL));
    if (pos < CAP){
      uint32_t idx = (uint32_t)hw*NA + (uint32_t)ch;
      cand[((size_t)b<<14) + pos] = ((uint64_t)k << 18) | (uint64_t)idx;
    }
  }
}

// ======== pass 4: bitonic sort, decomposed (identical (k,j) network) ========
__global__ __launch_bounds__(256) void bsort_local_k(uint64_t* __restrict__ buf){
  __shared__ uint64_t S[2048];
  int blk = blockIdx.x;
  int b = blk>>3, chunk = blk&7;
  uint64_t* A_ = buf + ((size_t)b<<14) + ((size_t)chunk<<11);
  int t = threadIdx.x;
  int gbase = chunk<<11;
  for (int i=t;i<2048;i+=256) S[i]=A_[i];
  __syncthreads();
  for (unsigned k=2;k<=2048u;k<<=1){
    for (unsigned j=k>>1;j>0;j>>=1){
      for (int i=t;i<2048;i+=256){
        int l = i ^ (int)j;
        if (l > i){
          bool asc = (((gbase+i) & (int)k)==0);
          uint64_t a=S[i], c=S[l];
          bool sw = asc ? (a>c) : (a<c);
          if (sw){ S[i]=c; S[l]=a; }
        }
      }
      __syncthreads();
    }
  }
  for (int i=t;i<2048;i+=256) A_[i]=S[i];
}

__global__ __launch_bounds__(256) void bsort_pass_k(uint64_t* __restrict__ buf, int k, int j){
  int p = blockIdx.x*256 + threadIdx.x;
  int b = p >> 13;
  int q = p & 8191;
  int i = ((q & ~(j-1))<<1) | (q & (j-1));
  int l = i + j;
  uint64_t* A_ = buf + ((size_t)b<<14);
  uint64_t a=A_[i], c=A_[l];
  bool asc = ((i & k)==0);
  bool sw = asc ? (a>c) : (a<c);
  if (sw){ A_[i]=c; A_[l]=a; }
}

__global__ __launch_bounds__(256) void bsort_finish_k(uint64_t* __restrict__ buf, int k){
  __shared__ uint64_t S[2048];
  int blk = blockIdx.x;
  int b = blk>>3, chunk = blk&7;
  uint64_t* A_ = buf + ((size_t)b<<14) + ((size_t)chunk<<11);
  int t = threadIdx.x;
  bool asc = (((chunk<<11) & k)==0);
  for (int i=t;i<2048;i+=256) S[i]=A_[i];
  __syncthreads();
  for (unsigned j=1024;j>0;j>>=1){
    for (int i=t;i<2048;i+=256){
      int l = i ^ (int)j;
      if (l > i){
        uint64_t a=S[i], c=S[l];
        bool sw = asc ? (a>c) : (a<c);
        if (sw){ S[i]=c; S[l]=a; }
      }
    }
    __syncthreads();
  }
  for (int i=t;i<2048;i+=256) A_[i]=S[i];
}

// -------- pass 5: decode top-12000 boxes (exact f32 ref arithmetic) --------
__global__ void extract_k(const uint64_t* __restrict__ cand2,
                          const float* __restrict__ deltas,
                          const float* __restrict__ iminfo,
                          float* __restrict__ tb){
  int g = blockIdx.x*256 + threadIdx.x;
  if (g >= NB*PRE) return;
  int b = g / PRE, j = g - b*PRE;
  uint64_t K = cand2[((size_t)b<<14) + j];
  uint32_t idx = (uint32_t)K & 0x3FFFFu;
  int ch = (int)(idx % NA);
  int hw = (int)(idx / NA);
  int w  = hw & (WF-1);
  int h  = hw >> 7;
  float sx = (float)(w*16), sy = (float)(h*16);
  float ax1 = c_ax1[ch]+sx, ay1 = c_ay1[ch]+sy, ax2 = c_ax2[ch]+sx, ay2 = c_ay2[ch]+sy;
  const float* dp = deltas + ((size_t)(b*4*NA + ch*4) << 14) + hw;
  float dx = dp[0], dy = dp[HW], dwv = dp[2*HW], dhv = dp[3*HW];
  float aw  = __fadd_rn(__fsub_rn(ax2,ax1),1.f);
  float ah  = __fadd_rn(__fsub_rn(ay2,ay1),1.f);
  float acx = __fadd_rn(ax1, __fmul_rn(0.5f,aw));
  float acy = __fadd_rn(ay1, __fmul_rn(0.5f,ah));
  float pcx = __fadd_rn(__fmul_rn(dx,aw), acx);
  float pcy = __fadd_rn(__fmul_rn(dy,ah), acy);
  float ew  = (float)exp((double)dwv);
  float eh  = (float)exp((double)dhv);
  float pw  = __fmul_rn(ew, aw);
  float ph  = __fmul_rn(eh, ah);
  float hx  = __fmul_rn(0.5f,pw), hy = __fmul_rn(0.5f,ph);
  float x1 = __fsub_rn(pcx,hx), y1 = __fsub_rn(pcy,hy);
  float x2 = __fadd_rn(pcx,hx), y2 = __fadd_rn(pcy,hy);
  float maxx = __fsub_rn(iminfo[b*3+1],1.f);
  float maxy = __fsub_rn(iminfo[b*3+0],1.f);
  x1 = fminf(fmaxf(x1,0.f),maxx); y1 = fminf(fmaxf(y1,0.f),maxy);
  x2 = fminf(fmaxf(x2,0.f),maxx); y2 = fminf(fmaxf(y2,0.f),maxy);
  float area = __fmul_rn(__fadd_rn(__fsub_rn(x2,x1),1.f), __fadd_rn(__fsub_rn(y2,y1),1.f));
  int o = b*PRE + j;
  tb[o]            = x1;
  tb[NB*PRE + o]   = y1;
  tb[2*NB*PRE + o] = x2;
  tb[3*NB*PRE + o] = y2;
  tb[4*NB*PRE + o] = area;
}

// -------- NMS phase a: chunk candidates vs kept boxes (coalesced kbox reads) --------
__global__ void cross_k(const float* __restrict__ tb, const float* __restrict__ kbox,
                        const uint32_t* __restrict__ meta, uint64_t* __restrict__ presup,
                        int base){
  int b  = blockIdx.y;
  int jl = blockIdx.x*256 + threadIdx.x;
  int j  = base + jl;
  bool valid = (j < PRE);
  float x1=0,y1=0,x2=0,y2=0,ar=0;
  if (valid){
    int o = b*PRE + j;
    x1=tb[o]; y1=tb[NB*PRE+o]; x2=tb[2*NB*PRE+o]; y2=tb[3*NB*PRE+o]; ar=tb[4*NB*PRE+o];
  }
  int nk = (int)meta[32+b];
  __shared__ float kx1[256],ky1[256],kx2[256],ky2[256],kar[256];
  bool supp = !valid;
  for (int k0=0; k0<nk; k0+=256){
    int kk = k0 + threadIdx.x;
    if (kk < nk){
      int o = b*POST + kk;
      kx1[threadIdx.x]=kbox[o];
      ky1[threadIdx.x]=kbox[NB*POST+o];
      kx2[threadIdx.x]=kbox[2*NB*POST+o];
      ky2[threadIdx.x]=kbox[3*NB*POST+o];
      kar[threadIdx.x]=kbox[4*NB*POST+o];
    }
    __syncthreads();
    int lim = min(256, nk-k0);
    if (!supp){
      for (int q=0;q<lim;q++){
        if (iou_gt(kx1[q],ky1[q],kx2[q],ky2[q],kar[q], x1,y1,x2,y2,ar)){ supp=true; break; }
      }
    }
    __syncthreads();
  }
  unsigned long long m = __ballot(supp);
  if ((threadIdx.x & 63)==0) presup[b*32 + (jl>>6)] = m;
}

// -------- NMS phase b: intra-chunk bit-matrix, row-per-thread (broadcast LDS reads) --------
__global__ __launch_bounds__(256) void intra_k(const float* __restrict__ tb,
                                               uint64_t* __restrict__ Mm, int base){
  int b  = blockIdx.y;
  int il = blockIdx.x*256 + threadIdx.x;
  __shared__ float4 sbx[CHUNK];
  __shared__ float  sar[CHUNK];
  for (int s = threadIdx.x; s < CHUNK; s += 256){
    int j = base + s;
    if (j < PRE){
      int o = b*PRE + j;
      sbx[s] = make_float4(tb[o], tb[NB*PRE+o], tb[2*NB*PRE+o], tb[3*NB*PRE+o]);
      sar[s] = tb[4*NB*PRE+o];
    } else { sbx[s] = make_float4(0.f,0.f,-10.f,-10.f); sar[s] = 1.f; }
  }
  __syncthreads();
  uint64_t* Mr = Mm + (((size_t)b*CHUNK) + (size_t)il)*32;
  int i = base + il;
  if (i >= PRE){
    for (int w=0; w<32; w++) Mr[w] = 0;
    return;
  }
  float4 bb = sbx[il];
  float  ar = sar[il];
  int w0 = il >> 6;
  for (int w=0; w<w0; w++) Mr[w] = 0;
  int jmax = PRE - base;
  for (int w=w0; w<32; w++){
    uint64_t bits = 0;
    int jb = w<<6;
    #pragma unroll 8
    for (int q=0; q<64; q++){
      int jl = jb + q;
      float4 cb = sbx[jl];
      bool s = (jl < jmax) && iou_gt(bb.x,bb.y,bb.z,bb.w,ar, cb.x,cb.y,cb.z,cb.w,sar[jl]);
      bits |= ((uint64_t)s) << q;
    }
    Mr[w] = bits;
  }
}

// -------- NMS phase c: streamed-LDS greedy scan --------
// M-chunk streamed through LDS in 16 sub-tiles of 128 rows; wave 0 runs the
// serial keep chain (identical decisions/order to validated versions); all
// M reads (tile + row-OR) hit LDS.
__global__ __launch_bounds__(256) void scan_k(const uint64_t* __restrict__ Mm,
                                              const uint64_t* __restrict__ presup,
                                              uint32_t* __restrict__ keep,
                                              uint32_t* __restrict__ meta,
                                              const float* __restrict__ tb,
                                              float* __restrict__ kbox,
                                              int base){
  int b = blockIdx.x;
  int t = threadIdx.x;
  int l = t & 63;
  int wv = t >> 6;
  __shared__ uint64_t sM[128*32];     // 32 KB: current 128-row sub-tile
  __shared__ int s_nk;
  const uint64_t* Mb = Mm + (size_t)b*CHUNK*32;
  uint64_t acc = ~0ULL;
  if (wv==0 && l<32) acc = presup[b*32+l];
  int nk0 = (int)meta[32+b];
  int nk = nk0;
  for (int s=0; s<16; s++){
    __syncthreads();                                  // sM reuse guard
    for (int i=t; i<4096; i+=256) sM[i] = Mb[(size_t)s*4096 + i];
    __syncthreads();
    if (wv==0){
      #pragma unroll
      for (int dw=0; dw<2; dw++){
        if (nk >= POST) break;
        int w = s*2 + dw;
        uint64_t tile = sM[(size_t)(((dw<<6)+l)*32 + w)];
        uint64_t cur  = __shfl(acc, w);
        uint64_t kmask = 0;
        while (cur != ~0ULL && nk < POST){
          int p = __ffsll((unsigned long long)(~cur)) - 1;
          if (l==0) keep[b*POST+nk] = (uint32_t)(base + w*64 + p);
          nk++;
          kmask |= (1ULL<<p);
          cur |= (1ULL<<p) | (uint64_t)__shfl(tile, p);
        }
        while (kmask){
          int p = __ffsll((unsigned long long)kmask) - 1;
          kmask &= kmask - 1ULL;
          if (l<32) acc |= sM[(size_t)(((dw<<6)+p)*32 + l)];
        }
      }
    }
  }
  if (t==0){ meta[32+b] = (uint32_t)nk; s_nk = nk; }
  __syncthreads();
  nk = s_nk;
  for (int i = nk0 + t; i < nk; i += 256){
    int j = (int)keep[b*POST+i];
    int o = b*PRE + j;
    int d = b*POST + i;
    kbox[d]            = tb[o];
    kbox[NB*POST + d]  = tb[NB*PRE+o];
    kbox[2*NB*POST + d]= tb[2*NB*PRE+o];
    kbox[3*NB*POST + d]= tb[3*NB*PRE+o];
    kbox[4*NB*POST + d]= tb[4*NB*PRE+o];
  }
}

// -------- output (f32) --------
__global__ void finalize_k(const float* __restrict__ tb, const uint32_t* __restrict__ keep,
                           const uint32_t* __restrict__ meta, float* __restrict__ out){
  int g = blockIdx.x*256 + threadIdx.x;
  if (g >= NB*POST) return;
  int b = g / POST, i = g - b*POST;
  float x1=0.f,y1=0.f,x2=0.f,y2=0.f;
  if (i < (int)meta[32+b]){
    int j = (int)keep[b*POST+i];
    int o = b*PRE + j;
    x1=tb[o]; y1=tb[NB*PRE+o]; x2=tb[2*NB*PRE+o]; y2=tb[3*NB*PRE+o];
  }
  float* op = out + (size_t)g*5;
  op[0]=(float)b; op[1]=x1; op[2]=y1; op[3]=x2; op[4]=y2;
}

extern "C" void kernel_launch(void* const* d_in, const int* in_sizes, int n_in,
                              void* d_out, int out_size, void* d_ws, size_t ws_size,
                              hipStream_t stream){
  (void)in_sizes; (void)n_in; (void)out_size; (void)ws_size;
  const float* scores = (const float*)d_in[0];
  const float* deltas = (const float*)d_in[1];
  const float* iminfo = (const float*)d_in[2];
  float* out = (float*)d_out;
  char* ws = (char*)d_ws;

  uint32_t* hist  = (uint32_t*)(ws + OFF_HIST);
  uint32_t* meta  = (uint32_t*)(ws + OFF_META);
  uint64_t* cand  = (uint64_t*)(ws + OFF_CAND);
  float*    tb    = (float*)   (ws + OFF_TB);
  uint32_t* keep  = (uint32_t*)(ws + OFF_KEEP);
  uint64_t* pres  = (uint64_t*)(ws + OFF_PRES);
  uint64_t* Mm    = (uint64_t*)(ws + OFF_M);
  float*    kbox  = (float*)   (ws + OFF_KBOX);

  hipMemsetAsync(ws + OFF_HIST, 0, SZ_HIST + SZ_META, stream);
  hipMemsetAsync(ws + OFF_CAND, 0xFF, SZ_CAND, stream);

  prep_k    <<<(NB*NTOT+255)/256, 256, 0, stream>>>(scores, hist);
  scanhist_k<<<NB, 1024, 0, stream>>>(hist, meta);
  gather_k  <<<NB*NTOT/256, 256, 0, stream>>>(scores, meta, cand);

  bsort_local_k<<<NB*8, 256, 0, stream>>>(cand);
  for (int k=4096; k<=16384; k<<=1){
    for (int j=k>>1; j>=2048; j>>=1)
      bsort_pass_k<<<NB*8192/256, 256, 0, stream>>>(cand, k, j);
    bsort_finish_k<<<NB*8, 256, 0, stream>>>(cand, k);
  }

  extract_k <<<(NB*PRE+255)/256, 256, 0, stream>>>(cand, deltas, iminfo, tb);
  for (int ph=0; ph<NPH; ph++){
    int base = ph*CHUNK;
    cross_k<<<dim3(CHUNK/256, NB), 256, 0, stream>>>(tb, kbox, meta, pres, base);
    intra_k<<<dim3(CHUNK/256, NB), 256, 0, stream>>>(tb, Mm, base);
    scan_k <<<NB, 256, 0, stream>>>(Mm, pres, keep, meta, tb, kbox, base);
  }
  finalize_k<<<(NB*POST+255)/256, 256, 0, stream>>>(tb, keep, meta, out);
}

// Round 15
// 3593.371 us; speedup vs baseline: 1.2014x; 1.2014x over previous
//
#include <hip/hip_runtime.h>
#include <stdint.h>
#include <math.h>

#define NB   16
#define HF   128
#define WF   128
#define NA   9
#define HW   (HF*WF)          // 16384
#define NTOT (HW*NA)          // 147456
#define PRE  12000
#define POST 2000
#define CAP  16384
#define CHUNK 2048
#define NPH  6

// ws layout (bytes)
#define OFF_HIST  0u
#define SZ_HIST   (NB*65536u*4u)            // 4,194,304
#define OFF_META  (OFF_HIST + SZ_HIST)
#define SZ_META   4096u   // words: [0..15] cutoff | [32..47] nk | [256+b*16] gather count
#define OFF_CAND  (OFF_META + SZ_META)
#define SZ_CAND   (NB*CAP*8u)               // 2,097,152
#define OFF_TB    (OFF_CAND + SZ_CAND)
#define SZ_TB     (5u*NB*PRE*4u)            // 3,840,000
#define OFF_KEEP  (OFF_TB + SZ_TB)
#define SZ_KEEP   (NB*POST*4u)              // 128,000
#define OFF_PRES  (OFF_KEEP + SZ_KEEP)
#define SZ_PRES   (NB*32u*8u)               // 4,096
#define OFF_M     (OFF_PRES + SZ_PRES)
#define SZ_M      ((size_t)NB*CHUNK*32u*8u) // 8,388,608 (x2 planes)
#define OFF_KBOX  (OFF_M + 2u*SZ_M)
#define SZ_KBOX   (5u*NB*POST*4u)           // 640,000   (total ~27.7 MB)

#define M_CNT(b)  (256 + (b)*16)

// base anchors = classic py-faster-rcnn table minus 1 (base [0,0,15,15]); a8.y2=359.
__constant__ float c_ax1[NA] = {-84.f,-176.f,-360.f,-56.f,-120.f,-248.f,-36.f,-80.f,-168.f};
__constant__ float c_ay1[NA] = {-40.f,-88.f,-184.f,-56.f,-120.f,-248.f,-80.f,-168.f,-344.f};
__constant__ float c_ax2[NA] = { 99.f, 191.f, 375.f, 71.f, 135.f, 263.f, 51.f, 95.f, 183.f};
__constant__ float c_ay2[NA] = { 55.f, 103.f, 199.f, 71.f, 135.f, 263.f, 95.f, 183.f, 359.f};

__device__ __forceinline__ uint32_t score_key(float f){
  uint32_t b = __float_as_uint(f);
  uint32_t u = (b & 0x80000000u) ? ~b : (b | 0x80000000u);
  return ~u;
}

__device__ __forceinline__ bool iou_gt(float ax1,float ay1,float ax2,float ay2,float aa,
                                       float bx1,float by1,float bx2,float by2,float ba){
  float xx1 = fmaxf(ax1,bx1);
  float yy1 = fmaxf(ay1,by1);
  float xx2 = fminf(ax2,bx2);
  float yy2 = fminf(ay2,by2);
  float w = fmaxf(__fadd_rn(__fsub_rn(xx2,xx1),1.0f), 0.0f);
  float h = fmaxf(__fadd_rn(__fsub_rn(yy2,yy1),1.0f), 0.0f);
  float inter = __fmul_rn(w,h);
  float denom = __fsub_rn(__fadd_rn(aa,ba), inter);
  float iou   = __fdiv_rn(inter, denom);
  return iou > 0.7f;
}

// -------- pass 1: histogram --------
__global__ void prep_k(const float* __restrict__ scores, uint32_t* __restrict__ hist){
  int g = blockIdx.x*256 + threadIdx.x;
  if (g >= NB*NTOT) return;
  int hw = g & (HW-1);
  int t  = g >> 14;
  int ch = t % NA;
  int b  = t / NA;
  float s = scores[((size_t)(b*2*NA + NA + ch) << 14) + hw];
  uint32_t k = score_key(s);
  atomicAdd(&hist[((uint32_t)b<<16) + (k>>16)], 1u);
}

// -------- pass 2: cutoff --------
__global__ __launch_bounds__(1024) void scanhist_k(const uint32_t* __restrict__ hist,
                                                   uint32_t* __restrict__ meta){
  int b = blockIdx.x, t = threadIdx.x;
  const uint32_t* hh = hist + ((uint32_t)b<<16);
  int base = t<<6;
  uint32_t s=0;
  for (int i=0;i<64;i++) s += hh[base+i];
  __shared__ uint32_t part[1024];
  part[t]=s; __syncthreads();
  for (int off=1; off<1024; off<<=1){
    uint32_t v = (t>=off)? part[t-off] : 0u;
    __syncthreads();
    part[t] += v;
    __syncthreads();
  }
  uint32_t incl = part[t], excl = incl - s;
  if (excl < PRE && incl >= PRE){
    uint32_t run = excl;
    for (int i=0;i<64;i++){
      run += hh[base+i];
      if (run >= PRE){ meta[b] = (uint32_t)(base+i); break; }
    }
  }
}

// -------- pass 3: gather --------
__global__ __launch_bounds__(256) void gather_k(const float* __restrict__ scores,
                                                uint32_t* __restrict__ meta,
                                                uint64_t* __restrict__ cand){
  int g = blockIdx.x*256 + threadIdx.x;
  int hw = g & (HW-1);
  int t  = g >> 14;
  int ch = t % NA;
  int b  = t / NA;
  float s = scores[((size_t)(b*2*NA + NA + ch) << 14) + hw];
  uint32_t k = score_key(s);
  bool sel = (k>>16) <= meta[b];
  unsigned long long m = __ballot(sel);
  int wid  = threadIdx.x >> 6;
  int lane = threadIdx.x & 63;
  __shared__ uint32_t woff[4];
  __shared__ uint32_t sbase;
  if (lane==0) woff[wid] = __popcll(m);
  __syncthreads();
  if (threadIdx.x==0){
    uint32_t a=0;
    #pragma unroll
    for (int i=0;i<4;i++){ uint32_t c=woff[i]; woff[i]=a; a+=c; }
    sbase = a ? atomicAdd(&meta[M_CNT(b)], a) : 0u;
  }
  __syncthreads();
  if (sel){
    uint32_t pos = sbase + woff[wid] + (uint32_t)__popcll(m & ((1ULL<<lane)-1ULL));
    if (pos < CAP){
      uint32_t idx = (uint32_t)hw*NA + (uint32_t)ch;
      cand[((size_t)b<<14) + pos] = ((uint64_t)k << 18) | (uint64_t)idx;
    }
  }
}

// ======== pass 4: bitonic sort, decomposed ========
__global__ __launch_bounds__(256) void bsort_local_k(uint64_t* __restrict__ buf){
  __shared__ uint64_t S[2048];
  int blk = blockIdx.x;
  int b = blk>>3, chunk = blk&7;
  uint64_t* A_ = buf + ((size_t)b<<14) + ((size_t)chunk<<11);
  int t = threadIdx.x;
  int gbase = chunk<<11;
  for (int i=t;i<2048;i+=256) S[i]=A_[i];
  __syncthreads();
  for (unsigned k=2;k<=2048u;k<<=1){
    for (unsigned j=k>>1;j>0;j>>=1){
      for (int i=t;i<2048;i+=256){
        int l = i ^ (int)j;
        if (l > i){
          bool asc = (((gbase+i) & (int)k)==0);
          uint64_t a=S[i], c=S[l];
          bool sw = asc ? (a>c) : (a<c);
          if (sw){ S[i]=c; S[l]=a; }
        }
      }
      __syncthreads();
    }
  }
  for (int i=t;i<2048;i+=256) A_[i]=S[i];
}

__global__ __launch_bounds__(256) void bsort_pass_k(uint64_t* __restrict__ buf, int k, int j){
  int p = blockIdx.x*256 + threadIdx.x;
  int b = p >> 13;
  int q = p & 8191;
  int i = ((q & ~(j-1))<<1) | (q & (j-1));
  int l = i + j;
  uint64_t* A_ = buf + ((size_t)b<<14);
  uint64_t a=A_[i], c=A_[l];
  bool asc = ((i & k)==0);
  bool sw = asc ? (a>c) : (a<c);
  if (sw){ A_[i]=c; A_[l]=a; }
}

__global__ __launch_bounds__(256) void bsort_finish_k(uint64_t* __restrict__ buf, int k){
  __shared__ uint64_t S[2048];
  int blk = blockIdx.x;
  int b = blk>>3, chunk = blk&7;
  uint64_t* A_ = buf + ((size_t)b<<14) + ((size_t)chunk<<11);
  int t = threadIdx.x;
  bool asc = (((chunk<<11) & k)==0);
  for (int i=t;i<2048;i+=256) S[i]=A_[i];
  __syncthreads();
  for (unsigned j=1024;j>0;j>>=1){
    for (int i=t;i<2048;i+=256){
      int l = i ^ (int)j;
      if (l > i){
        uint64_t a=S[i], c=S[l];
        bool sw = asc ? (a>c) : (a<c);
        if (sw){ S[i]=c; S[l]=a; }
      }
    }
    __syncthreads();
  }
  for (int i=t;i<2048;i+=256) A_[i]=S[i];
}

// -------- pass 5: decode top-12000 --------
__global__ void extract_k(const uint64_t* __restrict__ cand2,
                          const float* __restrict__ deltas,
                          const float* __restrict__ iminfo,
                          float* __restrict__ tb){
  int g = blockIdx.x*256 + threadIdx.x;
  if (g >= NB*PRE) return;
  int b = g / PRE, j = g - b*PRE;
  uint64_t K = cand2[((size_t)b<<14) + j];
  uint32_t idx = (uint32_t)K & 0x3FFFFu;
  int ch = (int)(idx % NA);
  int hw = (int)(idx / NA);
  int w  = hw & (WF-1);
  int h  = hw >> 7;
  float sx = (float)(w*16), sy = (float)(h*16);
  float ax1 = c_ax1[ch]+sx, ay1 = c_ay1[ch]+sy, ax2 = c_ax2[ch]+sx, ay2 = c_ay2[ch]+sy;
  const float* dp = deltas + ((size_t)(b*4*NA + ch*4) << 14) + hw;
  float dx = dp[0], dy = dp[HW], dwv = dp[2*HW], dhv = dp[3*HW];
  float aw  = __fadd_rn(__fsub_rn(ax2,ax1),1.f);
  float ah  = __fadd_rn(__fsub_rn(ay2,ay1),1.f);
  float acx = __fadd_rn(ax1, __fmul_rn(0.5f,aw));
  float acy = __fadd_rn(ay1, __fmul_rn(0.5f,ah));
  float pcx = __fadd_rn(__fmul_rn(dx,aw), acx);
  float pcy = __fadd_rn(__fmul_rn(dy,ah), acy);
  float ew  = (float)exp((double)dwv);
  float eh  = (float)exp((double)dhv);
  float pw  = __fmul_rn(ew, aw);
  float ph  = __fmul_rn(eh, ah);
  float hx  = __fmul_rn(0.5f,pw), hy = __fmul_rn(0.5f,ph);
  float x1 = __fsub_rn(pcx,hx), y1 = __fsub_rn(pcy,hy);
  float x2 = __fadd_rn(pcx,hx), y2 = __fadd_rn(pcy,hy);
  float maxx = __fsub_rn(iminfo[b*3+1],1.f);
  float maxy = __fsub_rn(iminfo[b*3+0],1.f);
  x1 = fminf(fmaxf(x1,0.f),maxx); y1 = fminf(fmaxf(y1,0.f),maxy);
  x2 = fminf(fmaxf(x2,0.f),maxx); y2 = fminf(fmaxf(y2,0.f),maxy);
  float area = __fmul_rn(__fadd_rn(__fsub_rn(x2,x1),1.f), __fadd_rn(__fsub_rn(y2,y1),1.f));
  int o = b*PRE + j;
  tb[o]            = x1;
  tb[NB*PRE + o]   = y1;
  tb[2*NB*PRE + o] = x2;
  tb[3*NB*PRE + o] = y2;
  tb[4*NB*PRE + o] = area;
}

// -------- NMS phase a: chunk candidates vs kept boxes (coalesced kbox) --------
__global__ void cross_k(const float* __restrict__ tb, const float* __restrict__ kbox,
                        const uint32_t* __restrict__ meta, uint64_t* __restrict__ presup,
                        int base){
  int b  = blockIdx.y;
  int jl = blockIdx.x*256 + threadIdx.x;
  int j  = base + jl;
  bool valid = (j < PRE);
  float x1=0,y1=0,x2=0,y2=0,ar=0;
  if (valid){
    int o = b*PRE + j;
    x1=tb[o]; y1=tb[NB*PRE+o]; x2=tb[2*NB*PRE+o]; y2=tb[3*NB*PRE+o]; ar=tb[4*NB*PRE+o];
  }
  int nk = (int)meta[32+b];
  __shared__ float kx1[256],ky1[256],kx2[256],ky2[256],kar[256];
  bool supp = !valid;
  for (int k0=0; k0<nk; k0+=256){
    int kk = k0 + threadIdx.x;
    if (kk < nk){
      int o = b*POST + kk;
      kx1[threadIdx.x]=kbox[o];
      ky1[threadIdx.x]=kbox[NB*POST+o];
      kx2[threadIdx.x]=kbox[2*NB*POST+o];
      ky2[threadIdx.x]=kbox[3*NB*POST+o];
      kar[threadIdx.x]=kbox[4*NB*POST+o];
    }
    __syncthreads();
    int lim = min(256, nk-k0);
    if (!supp){
      for (int q=0;q<lim;q++){
        if (iou_gt(kx1[q],ky1[q],kx2[q],ky2[q],kar[q], x1,y1,x2,y2,ar)){ supp=true; break; }
      }
    }
    __syncthreads();
  }
  unsigned long long m = __ballot(supp);
  if ((threadIdx.x & 63)==0) presup[b*32 + (jl>>6)] = m;
}

// -------- fused: scan(phase p) on blocks [0,nscan) ∥ intra(phase p+1) on the rest --------
__global__ __launch_bounds__(256) void fused_k(const uint64_t* __restrict__ Mscan,
                                               uint64_t* __restrict__ Mnext,
                                               const uint64_t* __restrict__ presup,
                                               uint32_t* __restrict__ keep,
                                               uint32_t* __restrict__ meta,
                                               const float* __restrict__ tb,
                                               float* __restrict__ kbox,
                                               int base_scan, int base_next, int nscan){
  __shared__ __align__(16) char smem[40960];
  __shared__ int s_nk, s_done;
  int t = threadIdx.x;

  if ((int)blockIdx.x < nscan){
    // ===== scan role: streamed-LDS greedy keep chain (bit-identical decisions) =====
    uint64_t* sM = (uint64_t*)smem;            // 32 KB: 128 rows x 32 words
    int b = blockIdx.x;
    int l = t & 63, wv = t >> 6;
    const uint64_t* Mb = Mscan + (size_t)b*CHUNK*32;
    uint64_t acc = ~0ULL;
    if (wv==0 && l<32) acc = presup[b*32+l];
    if (t==0) s_done = 0;
    int nk0 = (int)meta[32+b];
    int nk = nk0;
    for (int s=0; s<16; s++){
      __syncthreads();                         // publishes s_done & guards sM reuse
      if (s_done) break;                       // uniform
      const ulonglong2* src = (const ulonglong2*)(Mb + (size_t)s*4096);
      ulonglong2* dst = (ulonglong2*)sM;
      for (int i=t; i<2048; i+=256) dst[i] = src[i];
      __syncthreads();
      if (wv==0){
        #pragma unroll
        for (int dw=0; dw<2; dw++){
          if (nk >= POST) break;
          int w = (s<<1) + dw;
          uint64_t cur = __shfl(acc, w);
          while (cur != ~0ULL && nk < POST){
            int p = __ffsll((unsigned long long)(~cur)) - 1;
            if (l==0) keep[b*POST+nk] = (uint32_t)(base_scan + (w<<6) + p);
            nk++;
            int rbase = ((dw<<6)+p)*32;
            uint64_t supw = sM[rbase + w];      // broadcast LDS read (on chain)
            cur |= (1ULL<<p) | supw;
            if (l<32) acc |= sM[rbase + l];     // row-OR (off chain)
          }
        }
        if (l==0 && nk>=POST) s_done = 1;
      }
    }
    if (wv==0 && l==0){ meta[32+b] = (uint32_t)nk; s_nk = nk; }
    __syncthreads();
    int nkf = s_nk;
    for (int i = nk0 + t; i < nkf; i += 256){
      int j = (int)keep[b*POST+i];
      int o = b*PRE + j;
      int d = b*POST + i;
      kbox[d]            = tb[o];
      kbox[NB*POST + d]  = tb[NB*PRE+o];
      kbox[2*NB*POST + d]= tb[2*NB*PRE+o];
      kbox[3*NB*POST + d]= tb[3*NB*PRE+o];
      kbox[4*NB*POST + d]= tb[4*NB*PRE+o];
    }
  } else {
    // ===== intra role: bit-matrix for phase p+1 (row-per-thread, broadcast LDS) =====
    float4* sbx = (float4*)smem;               // 32 KB
    float*  sar = (float*)(smem + 32768);      // 8 KB
    int bid = (int)blockIdx.x - nscan;
    int b  = bid >> 3;
    int il = (bid & 7)*256 + t;
    int base = base_next;
    for (int s = t; s < CHUNK; s += 256){
      int j = base + s;
      if (j < PRE){
        int o = b*PRE + j;
        sbx[s] = make_float4(tb[o], tb[NB*PRE+o], tb[2*NB*PRE+o], tb[3*NB*PRE+o]);
        sar[s] = tb[4*NB*PRE+o];
      } else { sbx[s] = make_float4(0.f,0.f,-10.f,-10.f); sar[s] = 1.f; }
    }
    __syncthreads();
    uint64_t* Mr = Mnext + (((size_t)b*CHUNK) + (size_t)il)*32;
    int i = base + il;
    if (i >= PRE){
      for (int w=0; w<32; w++) Mr[w] = 0;
      return;
    }
    float4 bb = sbx[il];
    float  ar = sar[il];
    int w0 = il >> 6;
    for (int w=0; w<w0; w++) Mr[w] = 0;
    int jmax = PRE - base;
    for (int w=w0; w<32; w++){
      uint64_t bits = 0;
      int jb = w<<6;
      #pragma unroll 8
      for (int q=0; q<64; q++){
        int jl = jb + q;
        float4 cb = sbx[jl];
        bool s = (jl < jmax) && iou_gt(bb.x,bb.y,bb.z,bb.w,ar, cb.x,cb.y,cb.z,cb.w,sar[jl]);
        bits |= ((uint64_t)s) << q;
      }
      Mr[w] = bits;
    }
  }
}

// -------- output (f32) --------
__global__ void finalize_k(const float* __restrict__ tb, const uint32_t* __restrict__ keep,
                           const uint32_t* __restrict__ meta, float* __restrict__ out){
  int g = blockIdx.x*256 + threadIdx.x;
  if (g >= NB*POST) return;
  int b = g / POST, i = g - b*POST;
  float x1=0.f,y1=0.f,x2=0.f,y2=0.f;
  if (i < (int)meta[32+b]){
    int j = (int)keep[b*POST+i];
    int o = b*PRE + j;
    x1=tb[o]; y1=tb[NB*PRE+o]; x2=tb[2*NB*PRE+o]; y2=tb[3*NB*PRE+o];
  }
  float* op = out + (size_t)g*5;
  op[0]=(float)b; op[1]=x1; op[2]=y1; op[3]=x2; op[4]=y2;
}

extern "C" void kernel_launch(void* const* d_in, const int* in_sizes, int n_in,
                              void* d_out, int out_size, void* d_ws, size_t ws_size,
                              hipStream_t stream){
  (void)in_sizes; (void)n_in; (void)out_size; (void)ws_size;
  const float* scores = (const float*)d_in[0];
  const float* deltas = (const float*)d_in[1];
  const float* iminfo = (const float*)d_in[2];
  float* out = (float*)d_out;
  char* ws = (char*)d_ws;

  uint32_t* hist  = (uint32_t*)(ws + OFF_HIST);
  uint32_t* meta  = (uint32_t*)(ws + OFF_META);
  uint64_t* cand  = (uint64_t*)(ws + OFF_CAND);
  float*    tb    = (float*)   (ws + OFF_TB);
  uint32_t* keep  = (uint32_t*)(ws + OFF_KEEP);
  uint64_t* pres  = (uint64_t*)(ws + OFF_PRES);
  uint64_t* M0    = (uint64_t*)(ws + OFF_M);
  uint64_t* M1    = (uint64_t*)(ws + OFF_M + SZ_M);
  float*    kbox  = (float*)   (ws + OFF_KBOX);

  hipMemsetAsync(ws + OFF_HIST, 0, SZ_HIST + SZ_META, stream);
  hipMemsetAsync(ws + OFF_CAND, 0xFF, SZ_CAND, stream);

  prep_k    <<<(NB*NTOT+255)/256, 256, 0, stream>>>(scores, hist);
  scanhist_k<<<NB, 1024, 0, stream>>>(hist, meta);
  gather_k  <<<NB*NTOT/256, 256, 0, stream>>>(scores, meta, cand);

  bsort_local_k<<<NB*8, 256, 0, stream>>>(cand);
  for (int k=4096; k<=16384; k<<=1){
    for (int j=k>>1; j>=2048; j>>=1)
      bsort_pass_k<<<NB*8192/256, 256, 0, stream>>>(cand, k, j);
    bsort_finish_k<<<NB*8, 256, 0, stream>>>(cand, k);
  }

  extract_k <<<(NB*PRE+255)/256, 256, 0, stream>>>(cand, deltas, iminfo, tb);

  // prologue: intra for phase 0 (no scan blocks), then presup_0 (nk=0)
  fused_k<<<128, 256, 0, stream>>>(M1, M0, pres, keep, meta, tb, kbox, 0, 0, 0);
  cross_k<<<dim3(CHUNK/256, NB), 256, 0, stream>>>(tb, kbox, meta, pres, 0);

  for (int p=0; p<NPH; p++){
    uint64_t* Mcur = (p&1) ? M1 : M0;
    uint64_t* Mnxt = (p&1) ? M0 : M1;
    int nblk = (p < NPH-1) ? (16+128) : 16;
    fused_k<<<nblk, 256, 0, stream>>>(Mcur, Mnxt, pres, keep, meta, tb, kbox,
                                      p*CHUNK, (p+1)*CHUNK, 16);
    if (p < NPH-1)
      cross_k<<<dim3(CHUNK/256, NB), 256, 0, stream>>>(tb, kbox, meta, pres, (p+1)*CHUNK);
  }
  finalize_k<<<(NB*POST+255)/256, 256, 0, stream>>>(tb, keep, meta, out);
}

// Round 16
// 2412.316 us; speedup vs baseline: 1.7896x; 1.4896x over previous
//
#include <hip/hip_runtime.h>
#include <stdint.h>
#include <math.h>

#define NB   16
#define HF   128
#define WF   128
#define NA   9
#define HW   (HF*WF)          // 16384
#define NTOT (HW*NA)          // 147456
#define PRE  12000
#define POST 2000
#define CAP  16384
#define CHUNK 2048
#define NPH  6

// ws layout (bytes)
#define OFF_HIST  0u
#define SZ_HIST   (NB*65536u*4u)            // 4,194,304
#define OFF_META  (OFF_HIST + SZ_HIST)
#define SZ_META   4096u   // words: [0..15] cutoff | [32..47] nk | [256+b*16] gather count
#define OFF_CAND  (OFF_META + SZ_META)
#define SZ_CAND   (NB*CAP*8u)               // 2,097,152
#define OFF_TB    (OFF_CAND + SZ_CAND)
#define SZ_TB     (5u*NB*PRE*4u)            // 3,840,000
#define OFF_KEEP  (OFF_TB + SZ_TB)
#define SZ_KEEP   (NB*POST*4u)              // 128,000
#define OFF_PRES  (OFF_KEEP + SZ_KEEP)
#define SZ_PRES   (NB*32u*8u)               // 4,096
#define OFF_M     (OFF_PRES + SZ_PRES)
#define SZ_M      ((size_t)NB*CHUNK*32u*8u) // 8,388,608 (x2 planes)
#define OFF_KBOX  (OFF_M + 2u*SZ_M)
#define SZ_KBOX   (5u*NB*POST*4u)           // 640,000   (total ~27.7 MB)

#define M_CNT(b)  (256 + (b)*16)

// base anchors = classic py-faster-rcnn table minus 1 (base [0,0,15,15]); a8.y2=359.
__constant__ float c_ax1[NA] = {-84.f,-176.f,-360.f,-56.f,-120.f,-248.f,-36.f,-80.f,-168.f};
__constant__ float c_ay1[NA] = {-40.f,-88.f,-184.f,-56.f,-120.f,-248.f,-80.f,-168.f,-344.f};
__constant__ float c_ax2[NA] = { 99.f, 191.f, 375.f, 71.f, 135.f, 263.f, 51.f, 95.f, 183.f};
__constant__ float c_ay2[NA] = { 55.f, 103.f, 199.f, 71.f, 135.f, 263.f, 95.f, 183.f, 359.f};

__device__ __forceinline__ uint32_t score_key(float f){
  uint32_t b = __float_as_uint(f);
  uint32_t u = (b & 0x80000000u) ? ~b : (b | 0x80000000u);
  return ~u;
}

__device__ __forceinline__ bool iou_gt(float ax1,float ay1,float ax2,float ay2,float aa,
                                       float bx1,float by1,float bx2,float by2,float ba){
  float xx1 = fmaxf(ax1,bx1);
  float yy1 = fmaxf(ay1,by1);
  float xx2 = fminf(ax2,bx2);
  float yy2 = fminf(ay2,by2);
  float w = fmaxf(__fadd_rn(__fsub_rn(xx2,xx1),1.0f), 0.0f);
  float h = fmaxf(__fadd_rn(__fsub_rn(yy2,yy1),1.0f), 0.0f);
  float inter = __fmul_rn(w,h);
  float denom = __fsub_rn(__fadd_rn(aa,ba), inter);
  float iou   = __fdiv_rn(inter, denom);
  return iou > 0.7f;
}

// -------- pass 1: histogram --------
__global__ void prep_k(const float* __restrict__ scores, uint32_t* __restrict__ hist){
  int g = blockIdx.x*256 + threadIdx.x;
  if (g >= NB*NTOT) return;
  int hw = g & (HW-1);
  int t  = g >> 14;
  int ch = t % NA;
  int b  = t / NA;
  float s = scores[((size_t)(b*2*NA + NA + ch) << 14) + hw];
  uint32_t k = score_key(s);
  atomicAdd(&hist[((uint32_t)b<<16) + (k>>16)], 1u);
}

// -------- pass 2: cutoff --------
__global__ __launch_bounds__(1024) void scanhist_k(const uint32_t* __restrict__ hist,
                                                   uint32_t* __restrict__ meta){
  int b = blockIdx.x, t = threadIdx.x;
  const uint32_t* hh = hist + ((uint32_t)b<<16);
  int base = t<<6;
  uint32_t s=0;
  for (int i=0;i<64;i++) s += hh[base+i];
  __shared__ uint32_t part[1024];
  part[t]=s; __syncthreads();
  for (int off=1; off<1024; off<<=1){
    uint32_t v = (t>=off)? part[t-off] : 0u;
    __syncthreads();
    part[t] += v;
    __syncthreads();
  }
  uint32_t incl = part[t], excl = incl - s;
  if (excl < PRE && incl >= PRE){
    uint32_t run = excl;
    for (int i=0;i<64;i++){
      run += hh[base+i];
      if (run >= PRE){ meta[b] = (uint32_t)(base+i); break; }
    }
  }
}

// -------- pass 3: gather --------
__global__ __launch_bounds__(256) void gather_k(const float* __restrict__ scores,
                                                uint32_t* __restrict__ meta,
                                                uint64_t* __restrict__ cand){
  int g = blockIdx.x*256 + threadIdx.x;
  int hw = g & (HW-1);
  int t  = g >> 14;
  int ch = t % NA;
  int b  = t / NA;
  float s = scores[((size_t)(b*2*NA + NA + ch) << 14) + hw];
  uint32_t k = score_key(s);
  bool sel = (k>>16) <= meta[b];
  unsigned long long m = __ballot(sel);
  int wid  = threadIdx.x >> 6;
  int lane = threadIdx.x & 63;
  __shared__ uint32_t woff[4];
  __shared__ uint32_t sbase;
  if (lane==0) woff[wid] = __popcll(m);
  __syncthreads();
  if (threadIdx.x==0){
    uint32_t a=0;
    #pragma unroll
    for (int i=0;i<4;i++){ uint32_t c=woff[i]; woff[i]=a; a+=c; }
    sbase = a ? atomicAdd(&meta[M_CNT(b)], a) : 0u;
  }
  __syncthreads();
  if (sel){
    uint32_t pos = sbase + woff[wid] + (uint32_t)__popcll(m & ((1ULL<<lane)-1ULL));
    if (pos < CAP){
      uint32_t idx = (uint32_t)hw*NA + (uint32_t)ch;
      cand[((size_t)b<<14) + pos] = ((uint64_t)k << 18) | (uint64_t)idx;
    }
  }
}

// ======== pass 4: bitonic sort, decomposed ========
__global__ __launch_bounds__(256) void bsort_local_k(uint64_t* __restrict__ buf){
  __shared__ uint64_t S[2048];
  int blk = blockIdx.x;
  int b = blk>>3, chunk = blk&7;
  uint64_t* A_ = buf + ((size_t)b<<14) + ((size_t)chunk<<11);
  int t = threadIdx.x;
  int gbase = chunk<<11;
  for (int i=t;i<2048;i+=256) S[i]=A_[i];
  __syncthreads();
  for (unsigned k=2;k<=2048u;k<<=1){
    for (unsigned j=k>>1;j>0;j>>=1){
      for (int i=t;i<2048;i+=256){
        int l = i ^ (int)j;
        if (l > i){
          bool asc = (((gbase+i) & (int)k)==0);
          uint64_t a=S[i], c=S[l];
          bool sw = asc ? (a>c) : (a<c);
          if (sw){ S[i]=c; S[l]=a; }
        }
      }
      __syncthreads();
    }
  }
  for (int i=t;i<2048;i+=256) A_[i]=S[i];
}

__global__ __launch_bounds__(256) void bsort_pass_k(uint64_t* __restrict__ buf, int k, int j){
  int p = blockIdx.x*256 + threadIdx.x;
  int b = p >> 13;
  int q = p & 8191;
  int i = ((q & ~(j-1))<<1) | (q & (j-1));
  int l = i + j;
  uint64_t* A_ = buf + ((size_t)b<<14);
  uint64_t a=A_[i], c=A_[l];
  bool asc = ((i & k)==0);
  bool sw = asc ? (a>c) : (a<c);
  if (sw){ A_[i]=c; A_[l]=a; }
}

__global__ __launch_bounds__(256) void bsort_finish_k(uint64_t* __restrict__ buf, int k){
  __shared__ uint64_t S[2048];
  int blk = blockIdx.x;
  int b = blk>>3, chunk = blk&7;
  uint64_t* A_ = buf + ((size_t)b<<14) + ((size_t)chunk<<11);
  int t = threadIdx.x;
  bool asc = (((chunk<<11) & k)==0);
  for (int i=t;i<2048;i+=256) S[i]=A_[i];
  __syncthreads();
  for (unsigned j=1024;j>0;j>>=1){
    for (int i=t;i<2048;i+=256){
      int l = i ^ (int)j;
      if (l > i){
        uint64_t a=S[i], c=S[l];
        bool sw = asc ? (a>c) : (a<c);
        if (sw){ S[i]=c; S[l]=a; }
      }
    }
    __syncthreads();
  }
  for (int i=t;i<2048;i+=256) A_[i]=S[i];
}

// -------- pass 5: decode top-12000 --------
__global__ void extract_k(const uint64_t* __restrict__ cand2,
                          const float* __restrict__ deltas,
                          const float* __restrict__ iminfo,
                          float* __restrict__ tb){
  int g = blockIdx.x*256 + threadIdx.x;
  if (g >= NB*PRE) return;
  int b = g / PRE, j = g - b*PRE;
  uint64_t K = cand2[((size_t)b<<14) + j];
  uint32_t idx = (uint32_t)K & 0x3FFFFu;
  int ch = (int)(idx % NA);
  int hw = (int)(idx / NA);
  int w  = hw & (WF-1);
  int h  = hw >> 7;
  float sx = (float)(w*16), sy = (float)(h*16);
  float ax1 = c_ax1[ch]+sx, ay1 = c_ay1[ch]+sy, ax2 = c_ax2[ch]+sx, ay2 = c_ay2[ch]+sy;
  const float* dp = deltas + ((size_t)(b*4*NA + ch*4) << 14) + hw;
  float dx = dp[0], dy = dp[HW], dwv = dp[2*HW], dhv = dp[3*HW];
  float aw  = __fadd_rn(__fsub_rn(ax2,ax1),1.f);
  float ah  = __fadd_rn(__fsub_rn(ay2,ay1),1.f);
  float acx = __fadd_rn(ax1, __fmul_rn(0.5f,aw));
  float acy = __fadd_rn(ay1, __fmul_rn(0.5f,ah));
  float pcx = __fadd_rn(__fmul_rn(dx,aw), acx);
  float pcy = __fadd_rn(__fmul_rn(dy,ah), acy);
  float ew  = (float)exp((double)dwv);
  float eh  = (float)exp((double)dhv);
  float pw  = __fmul_rn(ew, aw);
  float ph  = __fmul_rn(eh, ah);
  float hx  = __fmul_rn(0.5f,pw), hy = __fmul_rn(0.5f,ph);
  float x1 = __fsub_rn(pcx,hx), y1 = __fsub_rn(pcy,hy);
  float x2 = __fadd_rn(pcx,hx), y2 = __fadd_rn(pcy,hy);
  float maxx = __fsub_rn(iminfo[b*3+1],1.f);
  float maxy = __fsub_rn(iminfo[b*3+0],1.f);
  x1 = fminf(fmaxf(x1,0.f),maxx); y1 = fminf(fmaxf(y1,0.f),maxy);
  x2 = fminf(fmaxf(x2,0.f),maxx); y2 = fminf(fmaxf(y2,0.f),maxy);
  float area = __fmul_rn(__fadd_rn(__fsub_rn(x2,x1),1.f), __fadd_rn(__fsub_rn(y2,y1),1.f));
  int o = b*PRE + j;
  tb[o]            = x1;
  tb[NB*PRE + o]   = y1;
  tb[2*NB*PRE + o] = x2;
  tb[3*NB*PRE + o] = y2;
  tb[4*NB*PRE + o] = area;
}

// -------- NMS phase a: 2D-tiled cross (cand-tile x keep-tile), atomicOr merge --------
// presup pre-initialized with validity bits by fused_k (scan role). Result words
// bit-identical to the serial formulation (same IoU set, OR is commutative).
__global__ __launch_bounds__(256) void cross2_k(const float* __restrict__ tb,
                                                const float* __restrict__ kbox,
                                                const uint32_t* __restrict__ meta,
                                                uint64_t* __restrict__ presup,
                                                int base){
  int b  = blockIdx.z;
  int nk = (int)meta[32+b];
  int kt = blockIdx.y*256;
  if (kt >= nk) return;
  __shared__ float kx1[256],ky1[256],kx2[256],ky2[256],kar[256];
  int tt = threadIdx.x;
  int kk = kt + tt;
  if (kk < nk){
    int o = b*POST + kk;
    kx1[tt]=kbox[o];
    ky1[tt]=kbox[NB*POST+o];
    kx2[tt]=kbox[2*NB*POST+o];
    ky2[tt]=kbox[3*NB*POST+o];
    kar[tt]=kbox[4*NB*POST+o];
  }
  __syncthreads();
  int jl = blockIdx.x*256 + tt;
  int j  = base + jl;
  bool supp = false;
  if (j < PRE){
    int o = b*PRE + j;
    float x1=tb[o], y1=tb[NB*PRE+o], x2=tb[2*NB*PRE+o], y2=tb[3*NB*PRE+o], ar=tb[4*NB*PRE+o];
    int lim = min(256, nk-kt);
    for (int q=0;q<lim;q++){
      if (iou_gt(kx1[q],ky1[q],kx2[q],ky2[q],kar[q], x1,y1,x2,y2,ar)){ supp=true; break; }
    }
  }
  unsigned long long m = __ballot(supp);
  if ((tt & 63)==0 && m)
    atomicOr((unsigned long long*)&presup[b*32 + (jl>>6)], m);
}

// -------- fused: scan(phase p) on blocks [0,nscan) ∥ intra(phase p+1) on the rest --------
__global__ __launch_bounds__(256) void fused_k(const uint64_t* __restrict__ Mscan,
                                               uint64_t* __restrict__ Mnext,
                                               uint64_t* __restrict__ presup,
                                               uint32_t* __restrict__ keep,
                                               uint32_t* __restrict__ meta,
                                               const float* __restrict__ tb,
                                               float* __restrict__ kbox,
                                               int base_scan, int base_next, int nscan){
  __shared__ __align__(16) char smem[40960];
  __shared__ int s_nk, s_done;
  int t = threadIdx.x;

  if ((int)blockIdx.x < nscan){
    // ===== scan role: streamed-LDS greedy keep chain (bit-identical decisions) =====
    uint64_t* sM = (uint64_t*)smem;            // 32 KB: 128 rows x 32 words
    int b = blockIdx.x;
    int l = t & 63, wv = t >> 6;
    const uint64_t* Mb = Mscan + (size_t)b*CHUNK*32;
    uint64_t acc = ~0ULL;
    if (wv==0 && l<32) acc = presup[b*32+l];
    if (t==0) s_done = 0;
    int nk0 = (int)meta[32+b];
    int nk = nk0;
    for (int s=0; s<16; s++){
      __syncthreads();
      if (s_done) break;
      const ulonglong2* src = (const ulonglong2*)(Mb + (size_t)s*4096);
      ulonglong2* dst = (ulonglong2*)sM;
      for (int i=t; i<2048; i+=256) dst[i] = src[i];
      __syncthreads();
      if (wv==0){
        #pragma unroll
        for (int dw=0; dw<2; dw++){
          if (nk >= POST) break;
          int w = (s<<1) + dw;
          uint64_t cur = __shfl(acc, w);
          while (cur != ~0ULL && nk < POST){
            int p = __ffsll((unsigned long long)(~cur)) - 1;
            if (l==0) keep[b*POST+nk] = (uint32_t)(base_scan + (w<<6) + p);
            nk++;
            int rbase = ((dw<<6)+p)*32;
            uint64_t supw = sM[rbase + w];
            cur |= (1ULL<<p) | supw;
            if (l<32) acc |= sM[rbase + l];
          }
        }
        if (l==0 && nk>=POST) s_done = 1;
      }
    }
    if (wv==0 && l==0){ meta[32+b] = (uint32_t)nk; s_nk = nk; }
    // re-init presup for the NEXT chunk with validity bits (cross2 atomicOrs on top)
    if (wv==0 && l<32){
      long rem = (long)PRE - (long)(base_next + (l<<6));
      uint64_t v = (rem >= 64) ? 0ULL : ((rem <= 0) ? ~0ULL : ~((1ULL<<rem) - 1ULL));
      presup[b*32 + l] = v;
    }
    __syncthreads();
    int nkf = s_nk;
    for (int i = nk0 + t; i < nkf; i += 256){
      int j = (int)keep[b*POST+i];
      int o = b*PRE + j;
      int d = b*POST + i;
      kbox[d]            = tb[o];
      kbox[NB*POST + d]  = tb[NB*PRE+o];
      kbox[2*NB*POST + d]= tb[2*NB*PRE+o];
      kbox[3*NB*POST + d]= tb[3*NB*PRE+o];
      kbox[4*NB*POST + d]= tb[4*NB*PRE+o];
    }
  } else {
    // ===== intra role: bit-matrix for phase p+1 (row-per-thread, broadcast LDS) =====
    float4* sbx = (float4*)smem;               // 32 KB
    float*  sar = (float*)(smem + 32768);      // 8 KB
    int bid = (int)blockIdx.x - nscan;
    int b  = bid >> 3;
    int il = (bid & 7)*256 + t;
    int base = base_next;
    for (int s = t; s < CHUNK; s += 256){
      int j = base + s;
      if (j < PRE){
        int o = b*PRE + j;
        sbx[s] = make_float4(tb[o], tb[NB*PRE+o], tb[2*NB*PRE+o], tb[3*NB*PRE+o]);
        sar[s] = tb[4*NB*PRE+o];
      } else { sbx[s] = make_float4(0.f,0.f,-10.f,-10.f); sar[s] = 1.f; }
    }
    __syncthreads();
    uint64_t* Mr = Mnext + (((size_t)b*CHUNK) + (size_t)il)*32;
    int i = base + il;
    if (i >= PRE){
      for (int w=0; w<32; w++) Mr[w] = 0;
      return;
    }
    float4 bb = sbx[il];
    float  ar = sar[il];
    int w0 = il >> 6;
    for (int w=0; w<w0; w++) Mr[w] = 0;
    int jmax = PRE - base;
    for (int w=w0; w<32; w++){
      uint64_t bits = 0;
      int jb = w<<6;
      #pragma unroll 8
      for (int q=0; q<64; q++){
        int jl = jb + q;
        float4 cb = sbx[jl];
        bool s = (jl < jmax) && iou_gt(bb.x,bb.y,bb.z,bb.w,ar, cb.x,cb.y,cb.z,cb.w,sar[jl]);
        bits |= ((uint64_t)s) << q;
      }
      Mr[w] = bits;
    }
  }
}

// -------- output (f32) --------
__global__ void finalize_k(const float* __restrict__ tb, const uint32_t* __restrict__ keep,
                           const uint32_t* __restrict__ meta, float* __restrict__ out){
  int g = blockIdx.x*256 + threadIdx.x;
  if (g >= NB*POST) return;
  int b = g / POST, i = g - b*POST;
  float x1=0.f,y1=0.f,x2=0.f,y2=0.f;
  if (i < (int)meta[32+b]){
    int j = (int)keep[b*POST+i];
    int o = b*PRE + j;
    x1=tb[o]; y1=tb[NB*PRE+o]; x2=tb[2*NB*PRE+o]; y2=tb[3*NB*PRE+o];
  }
  float* op = out + (size_t)g*5;
  op[0]=(float)b; op[1]=x1; op[2]=y1; op[3]=x2; op[4]=y2;
}

extern "C" void kernel_launch(void* const* d_in, const int* in_sizes, int n_in,
                              void* d_out, int out_size, void* d_ws, size_t ws_size,
                              hipStream_t stream){
  (void)in_sizes; (void)n_in; (void)out_size; (void)ws_size;
  const float* scores = (const float*)d_in[0];
  const float* deltas = (const float*)d_in[1];
  const float* iminfo = (const float*)d_in[2];
  float* out = (float*)d_out;
  char* ws = (char*)d_ws;

  uint32_t* hist  = (uint32_t*)(ws + OFF_HIST);
  uint32_t* meta  = (uint32_t*)(ws + OFF_META);
  uint64_t* cand  = (uint64_t*)(ws + OFF_CAND);
  float*    tb    = (float*)   (ws + OFF_TB);
  uint32_t* keep  = (uint32_t*)(ws + OFF_KEEP);
  uint64_t* pres  = (uint64_t*)(ws + OFF_PRES);
  uint64_t* M0    = (uint64_t*)(ws + OFF_M);
  uint64_t* M1    = (uint64_t*)(ws + OFF_M + SZ_M);
  float*    kbox  = (float*)   (ws + OFF_KBOX);

  hipMemsetAsync(ws + OFF_HIST, 0, SZ_HIST + SZ_META, stream);
  hipMemsetAsync(ws + OFF_CAND, 0xFF, SZ_CAND, stream);
  hipMemsetAsync(ws + OFF_PRES, 0, SZ_PRES, stream);   // chunk-0 presup: all valid

  prep_k    <<<(NB*NTOT+255)/256, 256, 0, stream>>>(scores, hist);
  scanhist_k<<<NB, 1024, 0, stream>>>(hist, meta);
  gather_k  <<<NB*NTOT/256, 256, 0, stream>>>(scores, meta, cand);

  bsort_local_k<<<NB*8, 256, 0, stream>>>(cand);
  for (int k=4096; k<=16384; k<<=1){
    for (int j=k>>1; j>=2048; j>>=1)
      bsort_pass_k<<<NB*8192/256, 256, 0, stream>>>(cand, k, j);
    bsort_finish_k<<<NB*8, 256, 0, stream>>>(cand, k);
  }

  extract_k <<<(NB*PRE+255)/256, 256, 0, stream>>>(cand, deltas, iminfo, tb);

  // prologue: intra for phase 0 only (presup_0 already zeroed = all-valid)
  fused_k<<<128, 256, 0, stream>>>(M1, M0, pres, keep, meta, tb, kbox, 0, 0, 0);

  for (int p=0; p<NPH; p++){
    uint64_t* Mcur = (p&1) ? M1 : M0;
    uint64_t* Mnxt = (p&1) ? M0 : M1;
    int nblk = (p < NPH-1) ? (16+128) : 16;
    fused_k<<<nblk, 256, 0, stream>>>(Mcur, Mnxt, pres, keep, meta, tb, kbox,
                                      p*CHUNK, (p+1)*CHUNK, 16);
    if (p < NPH-1)
      cross2_k<<<dim3(CHUNK/256, 8, NB), 256, 0, stream>>>(tb, kbox, meta, pres, (p+1)*CHUNK);
  }
  finalize_k<<<(NB*POST+255)/256, 256, 0, stream>>>(tb, keep, meta, out);
}